// Round 1
// baseline (483.639 us; speedup 1.0000x reference)
//
#include <hip/hip_runtime.h>
#include <math.h>

#define N_SRC 16384
#define M_REF 16384
#define DEMB  256
#define KNN_K 16

// ---------------- Kernel A: W_sym = triu(W) + triu(W)^T ----------------
__global__ void wsym_kernel(const float* __restrict__ W, float* __restrict__ wsym) {
    int i = blockIdx.x;
    int j = threadIdx.x;
    float a = (j >= i) ? W[i * DEMB + j] : 0.f;
    float b = (i >= j) ? W[j * DEMB + i] : 0.f;
    wsym[i * DEMB + j] = a + b;
}

// ---------------- Kernel B: q = src_feats @ W_sym  (fp32 vector GEMM) ----------------
// Block: 256 threads, handles 16 rows of src_feats. Thread d owns output column d.
// Uses symmetry: q[n][d] = sum_c sf[n][c] * W_sym[d][c]  (row d contiguous).
__global__ void __launch_bounds__(256) q_kernel(const float* __restrict__ src_feats,
                                                const float* __restrict__ wsym,
                                                float* __restrict__ q) {
    __shared__ __align__(16) float sf[16 * DEMB];
    int n0 = blockIdx.x * 16;
    int tid = threadIdx.x;
    #pragma unroll
    for (int t = 0; t < 16; ++t)
        sf[t * 256 + tid] = src_feats[(size_t)n0 * DEMB + t * 256 + tid];
    __syncthreads();

    float acc[16];
    #pragma unroll
    for (int i = 0; i < 16; ++i) acc[i] = 0.f;

    const float4* sfv  = (const float4*)sf;
    const float4* wrow = (const float4*)(wsym + (size_t)tid * DEMB);
    for (int c4 = 0; c4 < 64; ++c4) {
        float4 w4 = wrow[c4];
        #pragma unroll
        for (int i = 0; i < 16; ++i) {
            float4 s4 = sfv[i * 64 + c4];
            acc[i] = fmaf(s4.x, w4.x, acc[i]);
            acc[i] = fmaf(s4.y, w4.y, acc[i]);
            acc[i] = fmaf(s4.z, w4.z, acc[i]);
            acc[i] = fmaf(s4.w, w4.w, acc[i]);
        }
    }
    #pragma unroll
    for (int i = 0; i < 16; ++i)
        q[(size_t)(n0 + i) * DEMB + tid] = acc[i];
}

// ---------------- Kernel C: exact KNN (K=16) ----------------
// One wave (64 lanes) per src point; 4 waves per block.
// Pass 1: per-lane min -> bitonic sort of 64 lane-minima -> tau = 16th smallest
//         (upper bound on the true 16th distance: the 16 smallest lane-minima
//          are 16 distinct real distances).
// Pass 2: per-lane sorted top-16 insertion, gated by d2 <= tau (rare).
// Merge: 16x wave-argmin with (d2, idx) tie-break; winner shifts its list.
__global__ void __launch_bounds__(256) knn_kernel(const float* __restrict__ src_points,
                                                  const float* __restrict__ ref_points,
                                                  float* __restrict__ kd2,
                                                  int* __restrict__ kidx) {
    const float INF = 3.0e38f;
    int wave = threadIdx.x >> 6;
    int lane = threadIdx.x & 63;
    int n = blockIdx.x * 4 + wave;

    float sx = src_points[n * 3 + 0];
    float sy = src_points[n * 3 + 1];
    float sz = src_points[n * 3 + 2];

    // ---- pass 1: per-lane min ----
    float mind = INF;
    for (int i = lane; i < M_REF; i += 64) {
        float rx = ref_points[i * 3 + 0];
        float ry = ref_points[i * 3 + 1];
        float rz = ref_points[i * 3 + 2];
        float dx = sx - rx, dy = sy - ry, dz = sz - rz;
        float d2 = fmaf(dx, dx, fmaf(dy, dy, dz * dz));
        mind = fminf(mind, d2);
    }
    // bitonic sort 64 lane-minima (ascending across lanes)
    float v = mind;
    #pragma unroll
    for (int k = 2; k <= 64; k <<= 1) {
        #pragma unroll
        for (int j = k >> 1; j > 0; j >>= 1) {
            float o = __shfl_xor(v, j, 64);
            bool lower = (lane & j) == 0;
            bool up    = (lane & k) == 0;
            float mn = fminf(v, o), mx = fmaxf(v, o);
            v = (lower == up) ? mn : mx;
        }
    }
    float tau = __shfl(v, 15, 64);

    // ---- pass 2: per-lane sorted top-16, gated on tau ----
    float dv[16]; int iv[16];
    #pragma unroll
    for (int t = 0; t < 16; ++t) { dv[t] = INF; iv[t] = -1; }

    for (int i = lane; i < M_REF; i += 64) {
        float rx = ref_points[i * 3 + 0];
        float ry = ref_points[i * 3 + 1];
        float rz = ref_points[i * 3 + 2];
        float dx = sx - rx, dy = sy - ry, dz = sz - rz;
        float d2 = fmaf(dx, dx, fmaf(dy, dy, dz * dz));
        if (d2 <= tau && d2 < dv[15]) {
            // branchless sorted insertion (static indices only)
            #pragma unroll
            for (int t = 15; t > 0; --t) {
                bool shift = (dv[t - 1] > d2);
                float nd = shift ? dv[t - 1] : d2;
                int   ni = shift ? iv[t - 1] : i;
                bool  upd = (dv[t] > d2);
                dv[t] = upd ? nd : dv[t];
                iv[t] = upd ? ni : iv[t];
            }
            if (dv[0] > d2) { dv[0] = d2; iv[0] = i; }
        }
    }

    // ---- merge: extract 16 global smallest across the wave ----
    float resd = 0.f; int resi = 0;
    #pragma unroll
    for (int k = 0; k < KNN_K; ++k) {
        float bd = dv[0]; int bi = iv[0];
        #pragma unroll
        for (int off = 1; off < 64; off <<= 1) {
            float od = __shfl_xor(bd, off, 64);
            int   oi = __shfl_xor(bi, off, 64);
            if (od < bd || (od == bd && (unsigned)oi < (unsigned)bi)) { bd = od; bi = oi; }
        }
        bool won = (dv[0] == bd) && (iv[0] == bi);
        if (won) {
            #pragma unroll
            for (int t = 0; t < 15; ++t) { dv[t] = dv[t + 1]; iv[t] = iv[t + 1]; }
            dv[15] = INF; iv[15] = -1;
        }
        if (lane == k) { resd = bd; resi = bi; }
    }
    if (lane < KNN_K) {
        kd2[(size_t)n * KNN_K + lane] = resd;
        kidx[(size_t)n * KNN_K + lane] = resi;
    }
}

// ---------------- Kernel D: scores, softmax, corres, w ----------------
// One wave per src point. lane = k*4 + j : 16 neighbors x 4 lanes each.
__global__ void __launch_bounds__(256) score_kernel(const float* __restrict__ q,
                                                    const float* __restrict__ ref_feats,
                                                    const float* __restrict__ ref_points,
                                                    const float* __restrict__ src_points,
                                                    const float* __restrict__ kd2,
                                                    const int* __restrict__ kidx,
                                                    float* __restrict__ out) {
    int wave = threadIdx.x >> 6;
    int lane = threadIdx.x & 63;
    int n = blockIdx.x * 4 + wave;
    int k = lane >> 2;
    int j = lane & 3;

    int idx = kidx[(size_t)n * KNN_K + k];
    const float4* rf = (const float4*)(ref_feats + (size_t)idx * DEMB);
    const float4* qv = (const float4*)(q + (size_t)n * DEMB);

    float acc = 0.f;
    #pragma unroll
    for (int t = 0; t < 16; ++t) {
        float4 a = qv[j * 16 + t];
        float4 b = rf[j * 16 + t];
        acc = fmaf(a.x, b.x, fmaf(a.y, b.y, fmaf(a.z, b.z, fmaf(a.w, b.w, acc))));
    }
    // reduce the 4 lanes of this neighbor group
    acc += __shfl_xor(acc, 1, 64);
    acc += __shfl_xor(acc, 2, 64);

    float d2 = kd2[(size_t)n * KNN_K + k];
    float wt = fmaxf(0.f, fmaf(-2.f, d2, 1.f));   // relu(1 - d2/0.5)
    float tval = acc * wt;

    // softmax over k (bits 2..5 of lane): strided butterflies
    float m = tval;
    #pragma unroll
    for (int off = 4; off < 64; off <<= 1) m = fmaxf(m, __shfl_xor(m, off, 64));
    float e = expf(tval - m);
    float s = e;
    #pragma unroll
    for (int off = 4; off < 64; off <<= 1) s += __shfl_xor(s, off, 64);
    float attn = e / s;

    float rx = ref_points[idx * 3 + 0];
    float ry = ref_points[idx * 3 + 1];
    float rz = ref_points[idx * 3 + 2];
    float cx = attn * rx, cy = attn * ry, cz = attn * rz;
    #pragma unroll
    for (int off = 4; off < 64; off <<= 1) {
        cx += __shfl_xor(cx, off, 64);
        cy += __shfl_xor(cy, off, 64);
        cz += __shfl_xor(cz, off, 64);
    }

    if (lane == 0) {
        float ssx = src_points[n * 3 + 0];
        float ssy = src_points[n * 3 + 1];
        float ssz = src_points[n * 3 + 2];
        float dx = ssx - cx, dy = ssy - cy, dz = ssz - cz;
        float dist = sqrtf(fmaf(dx, dx, fmaf(dy, dy, dz * dz)));
        float w = fmaxf(0.f, fmaf(-2.f, dist, 1.f));
        out[(size_t)n * 3 + 0] = cx;
        out[(size_t)n * 3 + 1] = cy;
        out[(size_t)n * 3 + 2] = cz;
        out[(size_t)N_SRC * 3 + n] = w;
    }
}

extern "C" void kernel_launch(void* const* d_in, const int* in_sizes, int n_in,
                              void* d_out, int out_size, void* d_ws, size_t ws_size,
                              hipStream_t stream) {
    const float* ref_points = (const float*)d_in[0];
    const float* src_points = (const float*)d_in[1];
    const float* ref_feats  = (const float*)d_in[2];
    const float* src_feats  = (const float*)d_in[3];
    const float* W          = (const float*)d_in[4];
    float* out = (float*)d_out;

    float* wsym = (float*)d_ws;
    float* q    = wsym + DEMB * DEMB;
    float* kd2  = q + (size_t)N_SRC * DEMB;
    int*   kidx = (int*)(kd2 + (size_t)N_SRC * KNN_K);

    wsym_kernel<<<DEMB, DEMB, 0, stream>>>(W, wsym);
    q_kernel<<<N_SRC / 16, 256, 0, stream>>>(src_feats, wsym, q);
    knn_kernel<<<N_SRC / 4, 256, 0, stream>>>(src_points, ref_points, kd2, kidx);
    score_kernel<<<N_SRC / 4, 256, 0, stream>>>(q, ref_feats, ref_points, src_points, kd2, kidx, out);
}

// Round 2
// 322.731 us; speedup vs baseline: 1.4986x; 1.4986x over previous
//
#include <hip/hip_runtime.h>
#include <math.h>

#define N_SRC 16384
#define M_REF 16384
#define DEMB  256
#define KNN_K 16
#define BSRC  8     // src points per wave in knn
#define CAP   96    // candidate buffer per src point

// ---------------- Kernel A: W_sym = triu(W) + triu(W)^T ----------------
__global__ void wsym_kernel(const float* __restrict__ W, float* __restrict__ wsym) {
    int i = blockIdx.x;
    int j = threadIdx.x;
    float a = (j >= i) ? W[i * DEMB + j] : 0.f;
    float b = (i >= j) ? W[j * DEMB + i] : 0.f;
    wsym[i * DEMB + j] = a + b;
}

// ---------------- Kernel B: q = src_feats @ W_sym ----------------
// 256 threads/block, 32 rows of src_feats per block.
// Thread t: cols {c0, c0+64, c0+128, c0+192} (c0 = t&63), rows rg*8..rg*8+7 (rg = t>>6).
// Per c4 iter: 8 ds_read_b128 (broadcast) + 4 global float4 + 128 fma -> VALU-bound.
__global__ void __launch_bounds__(256) q_kernel(const float* __restrict__ src_feats,
                                                const float* __restrict__ wsym,
                                                float* __restrict__ q) {
    __shared__ __align__(16) float sf[32][DEMB];
    int n0 = blockIdx.x * 32;
    int tid = threadIdx.x;
    {
        int c = (tid & 63) * 4;
        int r0 = tid >> 6;
        #pragma unroll
        for (int rr = 0; rr < 8; ++rr) {
            int r = rr * 4 + r0;
            *(float4*)&sf[r][c] = *(const float4*)&src_feats[(size_t)(n0 + r) * DEMB + c];
        }
    }
    __syncthreads();

    int c0 = tid & 63;
    int rg = tid >> 6;
    float acc[8][4];
    #pragma unroll
    for (int rr = 0; rr < 8; ++rr)
        #pragma unroll
        for (int cc = 0; cc < 4; ++cc) acc[rr][cc] = 0.f;

    for (int c4 = 0; c4 < 64; ++c4) {
        float4 w[4];
        #pragma unroll
        for (int cc = 0; cc < 4; ++cc)
            w[cc] = *(const float4*)&wsym[(size_t)(c0 + cc * 64) * DEMB + c4 * 4];
        #pragma unroll
        for (int rr = 0; rr < 8; ++rr) {
            float4 s = *(const float4*)&sf[rg * 8 + rr][c4 * 4];
            #pragma unroll
            for (int cc = 0; cc < 4; ++cc) {
                acc[rr][cc] = fmaf(s.x, w[cc].x, acc[rr][cc]);
                acc[rr][cc] = fmaf(s.y, w[cc].y, acc[rr][cc]);
                acc[rr][cc] = fmaf(s.z, w[cc].z, acc[rr][cc]);
                acc[rr][cc] = fmaf(s.w, w[cc].w, acc[rr][cc]);
            }
        }
    }
    #pragma unroll
    for (int rr = 0; rr < 8; ++rr)
        #pragma unroll
        for (int cc = 0; cc < 4; ++cc)
            q[(size_t)(n0 + rg * 8 + rr) * DEMB + (c0 + cc * 64)] = acc[rr][cc];
}

// ---------------- bitonic sort of (d2, idx) pairs across 64 lanes ----------------
__device__ __forceinline__ void sort64_kv(float& vd, int& vi, int lane) {
    #pragma unroll
    for (int k = 2; k <= 64; k <<= 1) {
        #pragma unroll
        for (int j = k >> 1; j > 0; j >>= 1) {
            float od = __shfl_xor(vd, j, 64);
            int   oi = __shfl_xor(vi, j, 64);
            bool keep_min = (((lane & j) == 0) == ((lane & k) == 0));
            bool oless = (od < vd) || (od == vd && oi < vi);
            bool take = (keep_min == oless);
            vd = take ? od : vd;
            vi = take ? oi : vi;
        }
    }
}

// ---------------- Kernel C: exact KNN, 8 src per wave ----------------
// Pass 1: per-lane min of d2' = |r|^2 - 2 r.s per src -> bitonic -> tau (16th lane-min).
// Pass 2: append (d2' <= tau) candidates to LDS (expected ~25/src).
// Selection: bitonic top-16 over candidates, (d2, idx) lexicographic = jax tie-break.
__global__ void __launch_bounds__(256) knn_kernel(const float* __restrict__ src_points,
                                                  const float* __restrict__ ref_points,
                                                  float* __restrict__ kd2,
                                                  int* __restrict__ kidx) {
    const float INF = 3.0e38f;
    int wave = threadIdx.x >> 6;
    int lane = threadIdx.x & 63;
    int n0 = (blockIdx.x * 4 + wave) * BSRC;

    __shared__ float cd[4][BSRC][CAP];
    __shared__ int   ci[4][BSRC][CAP];
    __shared__ int   cnt[4][BSRC];

    if (lane < BSRC) cnt[wave][lane] = 0;

    // wave-uniform src constants
    float m2x[BSRC], m2y[BSRC], m2z[BSRC], sn2[BSRC];
    #pragma unroll
    for (int b = 0; b < BSRC; ++b) {
        float sx = src_points[(n0 + b) * 3 + 0];
        float sy = src_points[(n0 + b) * 3 + 1];
        float sz = src_points[(n0 + b) * 3 + 2];
        m2x[b] = -2.f * sx; m2y[b] = -2.f * sy; m2z[b] = -2.f * sz;
        sn2[b] = fmaf(sx, sx, fmaf(sy, sy, sz * sz));
    }
    __syncthreads();

    // ---- pass 1 ----
    float mind[BSRC];
    #pragma unroll
    for (int b = 0; b < BSRC; ++b) mind[b] = INF;
    for (int i = lane; i < M_REF; i += 64) {
        float rx = ref_points[i * 3 + 0];
        float ry = ref_points[i * 3 + 1];
        float rz = ref_points[i * 3 + 2];
        float rn2 = fmaf(rx, rx, fmaf(ry, ry, rz * rz));
        #pragma unroll
        for (int b = 0; b < BSRC; ++b) {
            float d = fmaf(rx, m2x[b], rn2);
            d = fmaf(ry, m2y[b], d);
            d = fmaf(rz, m2z[b], d);
            mind[b] = fminf(mind[b], d);
        }
    }

    float tau[BSRC];
    #pragma unroll
    for (int b = 0; b < BSRC; ++b) {
        float v = mind[b];
        #pragma unroll
        for (int k = 2; k <= 64; k <<= 1) {
            #pragma unroll
            for (int j = k >> 1; j > 0; j >>= 1) {
                float o = __shfl_xor(v, j, 64);
                bool lower = (lane & j) == 0;
                bool up = (lane & k) == 0;
                float mn = fminf(v, o), mx = fmaxf(v, o);
                v = (lower == up) ? mn : mx;
            }
        }
        tau[b] = __shfl(v, 15, 64);
    }

    // ---- pass 2 ----
    for (int i = lane; i < M_REF; i += 64) {
        float rx = ref_points[i * 3 + 0];
        float ry = ref_points[i * 3 + 1];
        float rz = ref_points[i * 3 + 2];
        float rn2 = fmaf(rx, rx, fmaf(ry, ry, rz * rz));
        #pragma unroll
        for (int b = 0; b < BSRC; ++b) {
            float d = fmaf(rx, m2x[b], rn2);
            d = fmaf(ry, m2y[b], d);
            d = fmaf(rz, m2z[b], d);
            if (d <= tau[b]) {
                int p = atomicAdd(&cnt[wave][b], 1);
                if (p < CAP) { cd[wave][b][p] = d; ci[wave][b][p] = i; }
            }
        }
    }
    __syncthreads();

    // ---- selection ----
    #pragma unroll
    for (int b = 0; b < BSRC; ++b) {
        int count = cnt[wave][b];
        if (count > CAP) count = CAP;
        float vd = (lane < count) ? cd[wave][b][lane] : INF;
        int   vi = (lane < count) ? ci[wave][b][lane] : 0x7fffffff;
        sort64_kv(vd, vi, lane);
        int done = 64;
        while (done < count) {            // essentially never taken
            if (lane >= 16) {
                int p = done + (lane - 16);
                vd = (p < count) ? cd[wave][b][p] : INF;
                vi = (p < count) ? ci[wave][b][p] : 0x7fffffff;
            }
            sort64_kv(vd, vi, lane);
            done += 48;
        }
        if (lane < KNN_K) {
            kd2[(size_t)(n0 + b) * KNN_K + lane] = vd + sn2[b];
            kidx[(size_t)(n0 + b) * KNN_K + lane] = vi;
        }
    }
}

// ---------------- Kernel D: scores, softmax, corres, w ----------------
// One wave per src point; lane owns 4 channels (float4 at c = lane*4).
__global__ void __launch_bounds__(256) score_kernel(const float* __restrict__ q,
                                                    const float* __restrict__ ref_feats,
                                                    const float* __restrict__ ref_points,
                                                    const float* __restrict__ src_points,
                                                    const float* __restrict__ kd2,
                                                    const int* __restrict__ kidx,
                                                    float* __restrict__ out) {
    int wave = threadIdx.x >> 6;
    int lane = threadIdx.x & 63;
    int n = blockIdx.x * 4 + wave;

    float4 qv = *(const float4*)&q[(size_t)n * DEMB + lane * 4];

    int idx[KNN_K]; float d2[KNN_K];
    #pragma unroll
    for (int k = 0; k < KNN_K; ++k) {
        idx[k] = kidx[(size_t)n * KNN_K + k];     // uniform -> s_load
        d2[k]  = kd2[(size_t)n * KNN_K + k];
    }

    float sc[KNN_K];
    #pragma unroll
    for (int k = 0; k < KNN_K; ++k) {
        float4 r = *(const float4*)&ref_feats[(size_t)idx[k] * DEMB + lane * 4];
        float p = fmaf(r.x, qv.x, fmaf(r.y, qv.y, fmaf(r.z, qv.z, r.w * qv.w)));
        #pragma unroll
        for (int off = 1; off < 64; off <<= 1) p += __shfl_xor(p, off, 64);
        sc[k] = p;
    }

    // softmax over k (all lanes hold identical values after butterfly)
    float tv[KNN_K];
    #pragma unroll
    for (int k = 0; k < KNN_K; ++k) {
        float wt = fmaxf(0.f, fmaf(-2.f, d2[k], 1.f));
        tv[k] = sc[k] * wt;
    }
    float m = tv[0];
    #pragma unroll
    for (int k = 1; k < KNN_K; ++k) m = fmaxf(m, tv[k]);
    float e[KNN_K], s = 0.f;
    #pragma unroll
    for (int k = 0; k < KNN_K; ++k) { e[k] = expf(tv[k] - m); s += e[k]; }

    float cx = 0.f, cy = 0.f, cz = 0.f;
    #pragma unroll
    for (int k = 0; k < KNN_K; ++k) {
        float rx = ref_points[idx[k] * 3 + 0];    // uniform -> s_load
        float ry = ref_points[idx[k] * 3 + 1];
        float rz = ref_points[idx[k] * 3 + 2];
        cx = fmaf(e[k], rx, cx);
        cy = fmaf(e[k], ry, cy);
        cz = fmaf(e[k], rz, cz);
    }
    float inv = 1.f / s;
    cx *= inv; cy *= inv; cz *= inv;

    if (lane == 0) {
        float ssx = src_points[n * 3 + 0];
        float ssy = src_points[n * 3 + 1];
        float ssz = src_points[n * 3 + 2];
        float dx = ssx - cx, dy = ssy - cy, dz = ssz - cz;
        float dist = sqrtf(fmaf(dx, dx, fmaf(dy, dy, dz * dz)));
        float w = fmaxf(0.f, fmaf(-2.f, dist, 1.f));
        out[(size_t)n * 3 + 0] = cx;
        out[(size_t)n * 3 + 1] = cy;
        out[(size_t)n * 3 + 2] = cz;
        out[(size_t)N_SRC * 3 + n] = w;
    }
}

extern "C" void kernel_launch(void* const* d_in, const int* in_sizes, int n_in,
                              void* d_out, int out_size, void* d_ws, size_t ws_size,
                              hipStream_t stream) {
    const float* ref_points = (const float*)d_in[0];
    const float* src_points = (const float*)d_in[1];
    const float* ref_feats  = (const float*)d_in[2];
    const float* src_feats  = (const float*)d_in[3];
    const float* W          = (const float*)d_in[4];
    float* out = (float*)d_out;

    float* wsym = (float*)d_ws;
    float* q    = wsym + DEMB * DEMB;
    float* kd2  = q + (size_t)N_SRC * DEMB;
    int*   kidx = (int*)(kd2 + (size_t)N_SRC * KNN_K);

    wsym_kernel<<<DEMB, DEMB, 0, stream>>>(W, wsym);
    q_kernel<<<N_SRC / 32, 256, 0, stream>>>(src_feats, wsym, q);
    knn_kernel<<<N_SRC / (BSRC * 4), 256, 0, stream>>>(src_points, ref_points, kd2, kidx);
    score_kernel<<<N_SRC / 4, 256, 0, stream>>>(q, ref_feats, ref_points, src_points, kd2, kidx, out);
}

// Round 3
// 172.150 us; speedup vs baseline: 2.8094x; 1.8747x over previous
//
#include <hip/hip_runtime.h>
#include <math.h>

#define N_SRC 16384
#define M_REF 16384
#define DEMB  256
#define KNN_K 16
#define CAP   128   // candidate buffer per src point (expected ~55, +9 sigma safe)

// ---------------- Kernel A: W_sym = triu(W) + triu(W)^T ----------------
__global__ void wsym_kernel(const float* __restrict__ W, float* __restrict__ wsym) {
    int i = blockIdx.x;
    int j = threadIdx.x;
    float a = (j >= i) ? W[i * DEMB + j] : 0.f;
    float b = (i >= j) ? W[j * DEMB + i] : 0.f;
    wsym[i * DEMB + j] = a + b;
}

// ---------------- Kernel A2: pack ref_points -> (x,y,z,|r|^2) ----------------
__global__ void pack_kernel(const float* __restrict__ rp, float4* __restrict__ out) {
    int i = blockIdx.x * 256 + threadIdx.x;
    float x = rp[i * 3 + 0], y = rp[i * 3 + 1], z = rp[i * 3 + 2];
    out[i] = make_float4(x, y, z, fmaf(x, x, fmaf(y, y, z * z)));
}

// ---------------- Kernel B: q = src_feats @ W_sym ----------------
// 16 rows/block, 256 threads. Thread (c0=t&63, rg=t>>6): rows rg*4..+3,
// cols c0+cc*64. Uses symmetry: W_sym row slice == column slice, so the
// per-iter weight loads are lane-consecutive (coalesced 256B).
__global__ void __launch_bounds__(256) q_kernel(const float* __restrict__ src_feats,
                                                const float* __restrict__ wsym,
                                                float* __restrict__ q) {
    __shared__ __align__(16) float sf[16][DEMB];
    int n0 = blockIdx.x * 16;
    int tid = threadIdx.x;
    int c0 = tid & 63;
    int rg = tid >> 6;
    {
        int c = c0 * 4;
        #pragma unroll
        for (int rr = 0; rr < 4; ++rr) {
            int r = rr * 4 + rg;
            *(float4*)&sf[r][c] = *(const float4*)&src_feats[(size_t)(n0 + r) * DEMB + c];
        }
    }
    __syncthreads();

    float acc[4][4];
    #pragma unroll
    for (int rr = 0; rr < 4; ++rr)
        #pragma unroll
        for (int cc = 0; cc < 4; ++cc) acc[rr][cc] = 0.f;

    for (int c4 = 0; c4 < 64; ++c4) {
        float wv[4][4];   // [j][cc] = W_sym[c4*4+j][c0+cc*64]  (== W_sym[c0+cc*64][c4*4+j])
        #pragma unroll
        for (int j = 0; j < 4; ++j)
            #pragma unroll
            for (int cc = 0; cc < 4; ++cc)
                wv[j][cc] = wsym[(size_t)(c4 * 4 + j) * DEMB + c0 + cc * 64];
        #pragma unroll
        for (int rr = 0; rr < 4; ++rr) {
            float4 s = *(const float4*)&sf[rg * 4 + rr][c4 * 4];
            #pragma unroll
            for (int cc = 0; cc < 4; ++cc) {
                float a = acc[rr][cc];
                a = fmaf(s.x, wv[0][cc], a);
                a = fmaf(s.y, wv[1][cc], a);
                a = fmaf(s.z, wv[2][cc], a);
                a = fmaf(s.w, wv[3][cc], a);
                acc[rr][cc] = a;
            }
        }
    }
    #pragma unroll
    for (int rr = 0; rr < 4; ++rr)
        #pragma unroll
        for (int cc = 0; cc < 4; ++cc)
            q[(size_t)(n0 + rg * 4 + rr) * DEMB + (c0 + cc * 64)] = acc[rr][cc];
}

// ---------------- bitonic sort of (d2, idx) pairs across 64 lanes ----------------
__device__ __forceinline__ void sort64_kv(float& vd, int& vi, int lane) {
    #pragma unroll
    for (int k = 2; k <= 64; k <<= 1) {
        #pragma unroll
        for (int j = k >> 1; j > 0; j >>= 1) {
            float od = __shfl_xor(vd, j, 64);
            int   oi = __shfl_xor(vi, j, 64);
            bool keep_min = (((lane & j) == 0) == ((lane & k) == 0));
            bool oless = (od < vd) || (od == vd && oi < vi);
            bool take = (keep_min == oless);
            vd = take ? od : vd;
            vi = take ? oi : vi;
        }
    }
}

// ---------------- Kernel C: exact KNN ----------------
// Block = 256 threads = 4 waves = 2 src-groups x 2 ref-halves. Each wave:
// 8 src points, scans its half (8192 refs) twice (tau pass + append pass).
// tau = 16th-smallest lane-min of the half (provable bound: those 16 minima
// are 16 distinct real distances in the half). Both halves append to one
// shared LDS buffer; exact bitonic top-16 with (d2,idx) tie-break.
__global__ void __launch_bounds__(256) knn_kernel(const float* __restrict__ src_points,
                                                  const float4* __restrict__ refp4,
                                                  float* __restrict__ kd2,
                                                  int* __restrict__ kidx) {
    const float INF = 3.0e38f;
    int tid = threadIdx.x;
    int wave = tid >> 6, lane = tid & 63;
    int g = wave & 1, h = wave >> 1;
    int n0 = blockIdx.x * 16 + g * 8;

    __shared__ float cd[2][8][CAP];
    __shared__ int   ci[2][8][CAP];
    __shared__ int   cnt[2][8];
    if (tid < 16) cnt[tid >> 3][tid & 7] = 0;

    float m2x[8], m2y[8], m2z[8], sn2[8];
    #pragma unroll
    for (int b = 0; b < 8; ++b) {
        float sx = src_points[(n0 + b) * 3 + 0];
        float sy = src_points[(n0 + b) * 3 + 1];
        float sz = src_points[(n0 + b) * 3 + 2];
        m2x[b] = -2.f * sx; m2y[b] = -2.f * sy; m2z[b] = -2.f * sz;
        sn2[b] = fmaf(sx, sx, fmaf(sy, sy, sz * sz));
    }
    __syncthreads();

    const int base = h * (M_REF / 2);

    // ---- pass 1: per-lane min (d2' = |r|^2 - 2 r.s), 2x unrolled ----
    float mind[8];
    #pragma unroll
    for (int b = 0; b < 8; ++b) mind[b] = INF;
    for (int it = 0; it < 128; it += 2) {
        float4 r0 = refp4[base + it * 64 + lane];
        float4 r1 = refp4[base + (it + 1) * 64 + lane];
        #pragma unroll
        for (int b = 0; b < 8; ++b) {
            float d0 = fmaf(r0.x, m2x[b], r0.w);
            d0 = fmaf(r0.y, m2y[b], d0);
            d0 = fmaf(r0.z, m2z[b], d0);
            float d1 = fmaf(r1.x, m2x[b], r1.w);
            d1 = fmaf(r1.y, m2y[b], d1);
            d1 = fmaf(r1.z, m2z[b], d1);
            mind[b] = fminf(mind[b], fminf(d0, d1));
        }
    }

    float tau[8];
    #pragma unroll
    for (int b = 0; b < 8; ++b) {
        float v = mind[b];
        #pragma unroll
        for (int k = 2; k <= 64; k <<= 1) {
            #pragma unroll
            for (int j = k >> 1; j > 0; j >>= 1) {
                float o = __shfl_xor(v, j, 64);
                bool lower = (lane & j) == 0;
                bool up = (lane & k) == 0;
                float mn = fminf(v, o), mx = fmaxf(v, o);
                v = (lower == up) ? mn : mx;
            }
        }
        tau[b] = __shfl(v, 15, 64);
    }

    // ---- pass 2: gated append ----
    for (int it = 0; it < 128; it += 2) {
        int i0 = base + it * 64 + lane;
        float4 r0 = refp4[i0];
        float4 r1 = refp4[i0 + 64];
        #pragma unroll
        for (int b = 0; b < 8; ++b) {
            float d0 = fmaf(r0.x, m2x[b], r0.w);
            d0 = fmaf(r0.y, m2y[b], d0);
            d0 = fmaf(r0.z, m2z[b], d0);
            float d1 = fmaf(r1.x, m2x[b], r1.w);
            d1 = fmaf(r1.y, m2y[b], d1);
            d1 = fmaf(r1.z, m2z[b], d1);
            if (d0 <= tau[b]) {
                int p = atomicAdd(&cnt[g][b], 1);
                if (p < CAP) { cd[g][b][p] = d0; ci[g][b][p] = i0; }
            }
            if (d1 <= tau[b]) {
                int p = atomicAdd(&cnt[g][b], 1);
                if (p < CAP) { cd[g][b][p] = d1; ci[g][b][p] = i0 + 64; }
            }
        }
    }
    __syncthreads();

    // ---- selection: wave (g,h) does group g, src h*4..h*4+3 ----
    #pragma unroll
    for (int bb = 0; bb < 4; ++bb) {
        int b = h * 4 + bb;
        int count = cnt[g][b];
        if (count > CAP) count = CAP;
        float vd = (lane < count) ? cd[g][b][lane] : INF;
        int   vi = (lane < count) ? ci[g][b][lane] : 0x7fffffff;
        sort64_kv(vd, vi, lane);
        int done = 64;
        while (done < count) {
            if (lane >= 16) {
                int p = done + (lane - 16);
                vd = (p < count) ? cd[g][b][p] : INF;
                vi = (p < count) ? ci[g][b][p] : 0x7fffffff;
            }
            sort64_kv(vd, vi, lane);
            done += 48;
        }
        if (lane < KNN_K) {
            kd2[(size_t)(n0 + b) * KNN_K + lane] = vd + sn2[b];
            kidx[(size_t)(n0 + b) * KNN_K + lane] = vi;
        }
    }
}

// ---------------- Kernel D: scores, softmax, corres, w ----------------
// One wave per src point; lane owns 4 channels (float4 at c = lane*4).
__global__ void __launch_bounds__(256) score_kernel(const float* __restrict__ q,
                                                    const float* __restrict__ ref_feats,
                                                    const float* __restrict__ ref_points,
                                                    const float* __restrict__ src_points,
                                                    const float* __restrict__ kd2,
                                                    const int* __restrict__ kidx,
                                                    float* __restrict__ out) {
    int wave = threadIdx.x >> 6;
    int lane = threadIdx.x & 63;
    int n = blockIdx.x * 4 + wave;

    float4 qv = *(const float4*)&q[(size_t)n * DEMB + lane * 4];

    int idx[KNN_K]; float d2[KNN_K];
    #pragma unroll
    for (int k = 0; k < KNN_K; ++k) {
        idx[k] = kidx[(size_t)n * KNN_K + k];     // uniform -> s_load
        d2[k]  = kd2[(size_t)n * KNN_K + k];
    }

    float sc[KNN_K];
    #pragma unroll
    for (int k = 0; k < KNN_K; ++k) {
        float4 r = *(const float4*)&ref_feats[(size_t)idx[k] * DEMB + lane * 4];
        float p = fmaf(r.x, qv.x, fmaf(r.y, qv.y, fmaf(r.z, qv.z, r.w * qv.w)));
        #pragma unroll
        for (int off = 1; off < 64; off <<= 1) p += __shfl_xor(p, off, 64);
        sc[k] = p;
    }

    float tv[KNN_K];
    #pragma unroll
    for (int k = 0; k < KNN_K; ++k) {
        float wt = fmaxf(0.f, fmaf(-2.f, d2[k], 1.f));
        tv[k] = sc[k] * wt;
    }
    float m = tv[0];
    #pragma unroll
    for (int k = 1; k < KNN_K; ++k) m = fmaxf(m, tv[k]);
    float e[KNN_K], s = 0.f;
    #pragma unroll
    for (int k = 0; k < KNN_K; ++k) { e[k] = expf(tv[k] - m); s += e[k]; }

    float cx = 0.f, cy = 0.f, cz = 0.f;
    #pragma unroll
    for (int k = 0; k < KNN_K; ++k) {
        float rx = ref_points[idx[k] * 3 + 0];
        float ry = ref_points[idx[k] * 3 + 1];
        float rz = ref_points[idx[k] * 3 + 2];
        cx = fmaf(e[k], rx, cx);
        cy = fmaf(e[k], ry, cy);
        cz = fmaf(e[k], rz, cz);
    }
    float inv = 1.f / s;
    cx *= inv; cy *= inv; cz *= inv;

    if (lane == 0) {
        float ssx = src_points[n * 3 + 0];
        float ssy = src_points[n * 3 + 1];
        float ssz = src_points[n * 3 + 2];
        float dx = ssx - cx, dy = ssy - cy, dz = ssz - cz;
        float dist = sqrtf(fmaf(dx, dx, fmaf(dy, dy, dz * dz)));
        float w = fmaxf(0.f, fmaf(-2.f, dist, 1.f));
        out[(size_t)n * 3 + 0] = cx;
        out[(size_t)n * 3 + 1] = cy;
        out[(size_t)n * 3 + 2] = cz;
        out[(size_t)N_SRC * 3 + n] = w;
    }
}

extern "C" void kernel_launch(void* const* d_in, const int* in_sizes, int n_in,
                              void* d_out, int out_size, void* d_ws, size_t ws_size,
                              hipStream_t stream) {
    const float* ref_points = (const float*)d_in[0];
    const float* src_points = (const float*)d_in[1];
    const float* ref_feats  = (const float*)d_in[2];
    const float* src_feats  = (const float*)d_in[3];
    const float* W          = (const float*)d_in[4];
    float* out = (float*)d_out;

    float*  wsym  = (float*)d_ws;
    float4* refp4 = (float4*)(wsym + DEMB * DEMB);
    float*  q     = (float*)(refp4 + M_REF);
    float*  kd2   = q + (size_t)N_SRC * DEMB;
    int*    kidx  = (int*)(kd2 + (size_t)N_SRC * KNN_K);

    wsym_kernel<<<DEMB, DEMB, 0, stream>>>(W, wsym);
    pack_kernel<<<M_REF / 256, 256, 0, stream>>>(ref_points, refp4);
    q_kernel<<<N_SRC / 16, 256, 0, stream>>>(src_feats, wsym, q);
    knn_kernel<<<N_SRC / 16, 256, 0, stream>>>(src_points, refp4, kd2, kidx);
    score_kernel<<<N_SRC / 4, 256, 0, stream>>>(q, ref_feats, ref_points, src_points, kd2, kidx, out);
}